// Round 9
// baseline (295.441 us; speedup 1.0000x reference)
//
#include <hip/hip_runtime.h>
#include <hip/hip_bf16.h>
#include <stdint.h>

// SimpleAttention: B=4, S=2048, D_IN=D_OUT=1024, fp32 in/out, bf16 MFMA compute.
// out = softmax((x@Wq+bq)(x@Wk+bk)^T / 32) @ (x@Wv+bv)
//
// R9 = R8 (B operand out of LDS, frag-ready pre-pack, register dbuf;
// A-only LDS dbuf 16KB) + fix: OUT_MODE 2 K-frag epilogue must use the
// BATCH-LOCAL row (s & 2047) -- batch offset was double-counted, corrupting
// K-frags for batches 1-3 and part of V.

#define Bsz 4
#define Ssz 2048
#define Dsz 1024

typedef __attribute__((ext_vector_type(8))) short short8;
typedef __attribute__((ext_vector_type(4))) float floatx4;
typedef const __attribute__((address_space(1))) void* gptr_t;
typedef __attribute__((address_space(3))) void* lptr_t;

__device__ __forceinline__ ushort f32_to_bf16(float f) {
    union { float f; uint32_t u; } c; c.f = f;
    uint32_t u = c.u;
    u += 0x7fffu + ((u >> 16) & 1u);
    return (ushort)(u >> 16);
}

// ---------------------------------------------------------------------------
// C = A(MxK) * Bfrag(N=128 per block)^T. bf16 in, fp32 acc. BK=32, 4 waves
// 2x2, each wave 4x4 of 16x16x32 MFMA. A: global_load_lds + XOR swizzle,
// double-buffered. B: frag-ready global loads, register double-buffered.
// Fragment def: element(lane,j) = Bt[ntile*16+(lane&15)][kch*32+(lane>>4)*8+j]
// OUT_MODE: 0 = f32 row-major, 1 = bf16 row-major, 2 = bf16 K-frag layout.
// ---------------------------------------------------------------------------
template <int OUT_MODE>
__device__ __forceinline__ void gemm128(
    int bx, int by,
    const ushort* __restrict__ A, int lda,
    const ushort* __restrict__ Bfrag, int KCHB,
    int K,
    void* __restrict__ Cout, int ldc,
    const float* __restrict__ bias, float alpha)
{
    __shared__ ushort lsA[2][128 * 32];   // 16 KB total

    const int tid  = threadIdx.x;          // 256 threads
    const int row0 = by * 128;
    const int col0 = bx * 128;

    const int lane = tid & 63;
    const int wave = tid >> 6;
    const int wr   = (wave >> 1) * 64;     // wave's 64x64 quadrant
    const int wc   = (wave & 1) * 64;
    const int m16  = lane & 15;
    const int quad = lane >> 4;
    const int ntile0 = bx * 8 + (wave & 1) * 4;

    floatx4 acc[4][4];
#pragma unroll
    for (int i = 0; i < 4; i++)
#pragma unroll
        for (int j = 0; j < 4; j++) acc[i][j] = (floatx4){0.f, 0.f, 0.f, 0.f};

    // A staging: thread t fills LDS (row=t>>2, slot=t&3); XOR swizzle: slot
    // holds global kchunk c = slot ^ ((row>>1)&3).
    const int srow = tid >> 2;
    const int skc  = (tid & 3) ^ ((srow >> 1) & 3);
    const ushort* ga = A + (size_t)(row0 + srow) * lda + skc * 8;

    // read-side swizzle for A fragment
    const int aoff = (quad ^ ((m16 >> 1) & 3)) * 8;

    // B frag pointers: one coalesced 16B/lane load per frag
#define BPTR(ni, kch) ((const short8*)(Bfrag + (((size_t)(ntile0 + (ni)) * KCHB + (kch)) * 64 + lane) * 8))

    short8 bcur[4], bnxt[4];
#pragma unroll
    for (int ni = 0; ni < 4; ni++) bcur[ni] = *BPTR(ni, 0);

    // prologue: stage A tile 0 into buffer 0
    __builtin_amdgcn_global_load_lds((gptr_t)(ga),                     (lptr_t)(lsA[0] + tid * 8),        16, 0, 0);
    __builtin_amdgcn_global_load_lds((gptr_t)(ga + (size_t)64 * lda), (lptr_t)(lsA[0] + 2048 + tid * 8), 16, 0, 0);

    for (int k0 = 0, kch = 0; k0 < K; k0 += 32, kch++) {
        const int cur = kch & 1;
        __syncthreads();   // buf[cur] staged; buf[cur^1] reads from last iter done
        if (k0 + 32 < K) {
            const int nxt = cur ^ 1;
            const int kn = k0 + 32;
            __builtin_amdgcn_global_load_lds((gptr_t)(ga + kn),                     (lptr_t)(lsA[nxt] + tid * 8),        16, 0, 0);
            __builtin_amdgcn_global_load_lds((gptr_t)(ga + kn + (size_t)64 * lda), (lptr_t)(lsA[nxt] + 2048 + tid * 8), 16, 0, 0);
#pragma unroll
            for (int ni = 0; ni < 4; ni++) bnxt[ni] = *BPTR(ni, kch + 1);
        }

        short8 af[4];
#pragma unroll
        for (int mi = 0; mi < 4; mi++)
            af[mi] = *(const short8*)&lsA[cur][(wr + mi * 16 + m16) * 32 + aoff];
#pragma unroll
        for (int mi = 0; mi < 4; mi++)
#pragma unroll
            for (int ni = 0; ni < 4; ni++)
                acc[mi][ni] = __builtin_amdgcn_mfma_f32_16x16x32_bf16(af[mi], bcur[ni], acc[mi][ni], 0, 0, 0);
#pragma unroll
        for (int ni = 0; ni < 4; ni++) bcur[ni] = bnxt[ni];
    }
#undef BPTR

    // epilogue: C/D layout = col(lane&15), row = quad*4 + reg
#pragma unroll
    for (int ni = 0; ni < 4; ni++) {
        const int gcol = col0 + wc + ni * 16 + m16;
        const float bv = bias ? bias[gcol] : 0.0f;
#pragma unroll
        for (int mi = 0; mi < 4; mi++) {
            const int grow0 = row0 + wr + mi * 16 + quad * 4;
#pragma unroll
            for (int j = 0; j < 4; j++) {
                float v = (acc[mi][ni][j] + bv) * alpha;
                if (OUT_MODE == 0) {
                    ((float*)Cout)[(size_t)(grow0 + j) * ldc + gcol] = v;
                } else if (OUT_MODE == 1) {
                    ((ushort*)Cout)[(size_t)(grow0 + j) * ldc + gcol] = f32_to_bf16(v);
                } else {
                    // K-frag layout for scores' B operand: n-dim = key row
                    // (BATCH-LOCAL: Cout already has the batch offset),
                    // k-dim = embed e. KCH = Dsz/32 = 32.
                    const int s = (grow0 + j) & (Ssz - 1), e = gcol;
                    const size_t off = (((size_t)(s >> 4) * 32 + (e >> 5)) * 64
                                        + ((e >> 3) & 3) * 16 + (s & 15)) * 8 + (e & 7);
                    ((ushort*)Cout)[off] = f32_to_bf16(v);
                }
            }
        }
    }
}

// ---------------------------------------------------------------------------
// prep: x fp32 -> bf16
__global__ __launch_bounds__(256) void k_cvt_x(const float* __restrict__ x, ushort* __restrict__ xb) {
    int i = (blockIdx.x * 256 + threadIdx.x) * 4;
    float4 v = *(const float4*)(x + i);
    ushort4 o;
    o.x = f32_to_bf16(v.x); o.y = f32_to_bf16(v.y);
    o.z = f32_to_bf16(v.z); o.w = f32_to_bf16(v.w);
    *(ushort4*)(xb + i) = o;
}

// prep: W [K][N] fp32 -> Wfrag bf16 (frag-ready, KCH=32), for Wq/Wk/Wv (z)
__global__ __launch_bounds__(256) void k_wt(const float* __restrict__ Wq, const float* __restrict__ Wk,
                                            const float* __restrict__ Wv, ushort* __restrict__ Wt) {
    __shared__ float tile[32][33];
    const int z = blockIdx.z;
    const float* W = (z == 0) ? Wq : ((z == 1) ? Wk : Wv);
    ushort* out = Wt + (size_t)z * Dsz * Dsz;
    const int kb = blockIdx.y * 32, nb = blockIdx.x * 32;
    const int tx = threadIdx.x, ty = threadIdx.y;   // 32x8
#pragma unroll
    for (int j = 0; j < 32; j += 8)
        tile[ty + j][tx] = W[(size_t)(kb + ty + j) * Dsz + nb + tx];
    __syncthreads();
    // write frag layout: element(nt,kch,q*16+nf,j) = W[kch*32+q*8+j][nt*16+nf]
    const int kch = kb >> 5;
    const int q = tx >> 3, jf = tx & 7;   // tx = k_local
#pragma unroll
    for (int i = 0; i < 4; i++) {
        const int nl = ty + 8 * i;
        const int nt = (nb + nl) >> 4, nf = nl & 15;
        out[(((size_t)nt * 32 + kch) * 64 + q * 16 + nf) * 8 + jf] = f32_to_bf16(tile[tx][nl]);
    }
}

// QKV projection. Grid (8, 64, 3), R7 XCD swizzle. z=0: Q row-major (alpha
// 1/32 folded). z=1: K written frag-ready (batch-local). z=2: V row-major.
__global__ __launch_bounds__(256) void k_qkv(const ushort* __restrict__ xb, const ushort* __restrict__ Wt,
                                             const float* __restrict__ bq, const float* __restrict__ bk,
                                             const float* __restrict__ bv, ushort* __restrict__ QKV) {
    const int z = blockIdx.z;
    const int lin = blockIdx.y * 8 + blockIdx.x;   // 0..511
    const int c = lin & 7, m = lin >> 3;           // m 0..63
    const int by = 8 * c + (m & 7);
    const int bx = m >> 3;
    const ushort* Bf = Wt + (size_t)z * Dsz * Dsz;
    const float* bias = (z == 0) ? bq : ((z == 1) ? bk : bv);
    ushort* out = QKV + (size_t)z * (Bsz * Ssz) * Dsz;
    if (z == 0)
        gemm128<1>(bx, by, xb, Dsz, Bf, 32, Dsz, out, Dsz, bias, 0.03125f);
    else if (z == 1) {
        // per-batch frag buffers: batch = by>>4 (16 row-tiles per batch)
        ushort* outb = out + (size_t)(by >> 4) * Ssz * Dsz;
        gemm128<2>(bx, by, xb, Dsz, Bf, 32, Dsz, outb, Dsz, bias, 1.0f);
    } else
        gemm128<1>(bx, by, xb, Dsz, Bf, 32, Dsz, out, Dsz, bias, 1.0f);
}

// scores[b] = Q[b] @ K[b]^T. Grid (16, 16, 4), R7 XCD swizzle. B = Kfrag.
__global__ __launch_bounds__(256) void k_scores(const ushort* __restrict__ QKV, float* __restrict__ scores) {
    const int b = blockIdx.z;
    const int lin = blockIdx.y * 16 + blockIdx.x;  // 0..255
    const int c = lin & 7, m = lin >> 3;           // m 0..31
    const int by = 2 * c + (m & 1);
    const int bx = m >> 1;                         // 0..15
    const ushort* Q = QKV + (size_t)b * Ssz * Dsz;
    const ushort* Kf = QKV + (size_t)(Bsz + b) * Ssz * Dsz;
    gemm128<0>(bx, by, Q, Dsz, Kf, 32, Dsz, scores + (size_t)b * Ssz * Ssz, Ssz, nullptr, 1.0f);
}

// row softmax, fp32 row -> bf16 P written in place over the row's first half
__global__ __launch_bounds__(256) void k_softmax(float* __restrict__ scores) {
    const size_t row = blockIdx.x;
    float* rp = scores + row * Ssz;
    const int tid = threadIdx.x;
    float4 v0 = ((const float4*)rp)[tid];
    float4 v1 = ((const float4*)rp)[tid + 256];
    float m = fmaxf(fmaxf(fmaxf(v0.x, v0.y), fmaxf(v0.z, v0.w)),
                    fmaxf(fmaxf(v1.x, v1.y), fmaxf(v1.z, v1.w)));
#pragma unroll
    for (int o = 32; o > 0; o >>= 1) m = fmaxf(m, __shfl_down(m, o, 64));
    __shared__ float redm[4];
    if ((tid & 63) == 0) redm[tid >> 6] = m;
    __syncthreads();
    const float rm = fmaxf(fmaxf(redm[0], redm[1]), fmaxf(redm[2], redm[3]));
    v0.x = __expf(v0.x - rm); v0.y = __expf(v0.y - rm);
    v0.z = __expf(v0.z - rm); v0.w = __expf(v0.w - rm);
    v1.x = __expf(v1.x - rm); v1.y = __expf(v1.y - rm);
    v1.z = __expf(v1.z - rm); v1.w = __expf(v1.w - rm);
    float s = v0.x + v0.y + v0.z + v0.w + v1.x + v1.y + v1.z + v1.w;
#pragma unroll
    for (int o = 32; o > 0; o >>= 1) s += __shfl_down(s, o, 64);
    __shared__ float reds[4];
    if ((tid & 63) == 0) reds[tid >> 6] = s;
    __syncthreads();
    const float inv = 1.0f / (reds[0] + reds[1] + reds[2] + reds[3]);
    ushort4 o0, o1;
    o0.x = f32_to_bf16(v0.x * inv); o0.y = f32_to_bf16(v0.y * inv);
    o0.z = f32_to_bf16(v0.z * inv); o0.w = f32_to_bf16(v0.w * inv);
    o1.x = f32_to_bf16(v1.x * inv); o1.y = f32_to_bf16(v1.y * inv);
    o1.z = f32_to_bf16(v1.z * inv); o1.w = f32_to_bf16(v1.w * inv);
    ((ushort4*)rp)[tid] = o0;
    ((ushort4*)rp)[tid + 256] = o1;
}

// V [b][s][d] bf16 row-major -> Vfrag (frag-ready, KCH=64)
__global__ __launch_bounds__(256) void k_vt(const ushort* __restrict__ V, ushort* __restrict__ Vt) {
    __shared__ ushort tile[32][33];
    const int b = blockIdx.z;
    const ushort* Vb = V + (size_t)b * Ssz * Dsz;
    ushort* Vtb = Vt + (size_t)b * Dsz * Ssz;
    const int sb = blockIdx.y * 32, db = blockIdx.x * 32;
    const int tx = threadIdx.x, ty = threadIdx.y;
#pragma unroll
    for (int j = 0; j < 32; j += 8)
        tile[ty + j][tx] = Vb[(size_t)(sb + ty + j) * Dsz + db + tx];
    __syncthreads();
    // frag element(nt,kch,q*16+nf,j) = V[kch*32+q*8+j][nt*16+nf]
    const int kch = sb >> 5;
    const int q = tx >> 3, jf = tx & 7;   // tx = s_local
#pragma unroll
    for (int i = 0; i < 4; i++) {
        const int el = ty + 8 * i;
        const int nt = (db + el) >> 4, nf = el & 15;
        Vtb[(((size_t)nt * 64 + kch) * 64 + q * 16 + nf) * 8 + jf] = tile[tx][el];
    }
}

// out[b] = P[b] @ V[b]. Grid (8, 16, 4), R7 XCD swizzle. B = Vfrag, KCH=64.
__global__ __launch_bounds__(256) void k_pv(const float* __restrict__ scores, const ushort* __restrict__ Vt,
                                            float* __restrict__ out) {
    const int b = blockIdx.z;
    const int lin = blockIdx.y * 8 + blockIdx.x;   // 0..127
    const int c = lin & 7, m = lin >> 3;           // m 0..15
    const int by = 2 * c + (m & 1);
    const int bx = m >> 1;                         // 0..7
    const ushort* P = (const ushort*)(scores + (size_t)b * Ssz * Ssz);
    const ushort* Bf = Vt + (size_t)b * Dsz * Ssz;
    gemm128<0>(bx, by, P, 2 * Ssz, Bf, 64, Ssz, out + (size_t)b * Ssz * Dsz, Dsz, nullptr, 1.0f);
}

// ---------------------------------------------------------------------------
extern "C" void kernel_launch(void* const* d_in, const int* in_sizes, int n_in,
                              void* d_out, int out_size, void* d_ws, size_t ws_size,
                              hipStream_t stream) {
    const float* x  = (const float*)d_in[0];
    const float* Wq = (const float*)d_in[1];
    const float* bq = (const float*)d_in[2];
    const float* Wk = (const float*)d_in[3];
    const float* bk = (const float*)d_in[4];
    const float* Wv = (const float*)d_in[5];
    const float* bv = (const float*)d_in[6];
    float* out = (float*)d_out;

    // workspace layout (bytes)
    char* ws = (char*)d_ws;
    ushort* xb     = (ushort*)(ws);                                   // 16,777,216
    ushort* Wt     = (ushort*)(ws + 16777216);                        //  6,291,456
    ushort* QKV    = (ushort*)(ws + 23068672);                        // 50,331,648
    ushort* Vt     = (ushort*)(ws + 73400320);                        // 16,777,216
    float*  scores = (float*) (ws + 90177536);                        // 67,108,864 -> 157,286,400 total

    k_cvt_x<<<dim3(Bsz * Ssz * Dsz / (256 * 4)), dim3(256), 0, stream>>>(x, xb);
    k_wt<<<dim3(32, 32, 3), dim3(32, 8), 0, stream>>>(Wq, Wk, Wv, Wt);
    k_qkv<<<dim3(Dsz / 128, Bsz * Ssz / 128, 3), dim3(256), 0, stream>>>(xb, Wt, bq, bk, bv, QKV);
    k_vt<<<dim3(Dsz / 32, Ssz / 32, Bsz), dim3(32, 8), 0, stream>>>(QKV + (size_t)2 * Bsz * Ssz * Dsz, Vt);
    k_scores<<<dim3(Ssz / 128, Ssz / 128, Bsz), dim3(256), 0, stream>>>(QKV, scores);
    k_softmax<<<dim3(Bsz * Ssz), dim3(256), 0, stream>>>(scores);
    k_pv<<<dim3(Dsz / 128, Ssz / 128, Bsz), dim3(256), 0, stream>>>(scores, Vt, out);
}

// Round 10
// 277.514 us; speedup vs baseline: 1.0646x; 1.0646x over previous
//
#include <hip/hip_runtime.h>
#include <hip/hip_bf16.h>
#include <stdint.h>

// SimpleAttention: B=4, S=2048, D_IN=D_OUT=1024, fp32 in/out, bf16 MFMA compute.
// out = softmax((x@Wq+bq)(x@Wk+bk)^T / 32) @ (x@Wv+bv)
//
// R10: fused-QKV projection. One block does Q,K,V for its 128-row strip:
// A staged/read once for 3x MFMA (512 B/MFMA vs 768). bx==XCD keeps the
// 2.25MB W-slice L2-resident. V written pre-transposed (k_vt eliminated).
// scores/softmax/pv keep the R7 structure (R9's B-out-of-LDS regressed:
// VALU 54%). XOR LDS swizzle throughout (conflicts measured 0).

#define Bsz 4
#define Ssz 2048
#define Dsz 1024

typedef __attribute__((ext_vector_type(8))) short short8;
typedef __attribute__((ext_vector_type(4))) float floatx4;
typedef const __attribute__((address_space(1))) void* gptr_t;
typedef __attribute__((address_space(3))) void* lptr_t;

__device__ __forceinline__ ushort f32_to_bf16(float f) {
    union { float f; uint32_t u; } c; c.f = f;
    uint32_t u = c.u;
    u += 0x7fffu + ((u >> 16) & 1u);
    return (ushort)(u >> 16);
}

// ---------------------------------------------------------------------------
// Fused QKV: C_z = xb(128xK) * Wt_z(128xK)^T for z=0,1,2. BK=32, dbuf,
// one barrier/iter. 4 waves 2x2; wave does 4x4 of 16x16x32 MFMA per z.
// ---------------------------------------------------------------------------
__global__ __launch_bounds__(256, 2) void k_qkv(
    const ushort* __restrict__ xb, const ushort* __restrict__ Wt,
    const float* __restrict__ bq, const float* __restrict__ bk,
    const float* __restrict__ bv, ushort* __restrict__ QKV,
    ushort* __restrict__ Vt)
{
    __shared__ ushort lsA[2][128 * 32];      // 16 KB
    __shared__ ushort lsB[2][3][128 * 32];   // 48 KB

    const int tid  = threadIdx.x;
    const int bx   = blockIdx.x;             // 0..7  == XCD (lin%8)
    const int by   = blockIdx.y;             // 0..63
    const int row0 = by * 128;
    const int col0 = bx * 128;

    const int lane = tid & 63;
    const int wave = tid >> 6;
    const int wr   = (wave >> 1) * 64;
    const int wc   = (wave & 1) * 64;
    const int m16  = lane & 15;
    const int quad = lane >> 4;

    floatx4 acc[3][4][4];
#pragma unroll
    for (int z = 0; z < 3; z++)
#pragma unroll
        for (int i = 0; i < 4; i++)
#pragma unroll
            for (int j = 0; j < 4; j++) acc[z][i][j] = (floatx4){0.f, 0.f, 0.f, 0.f};

    // staging source (XOR swizzle: slot holds kchunk (slot)^((row>>1)&3))
    const int srow = tid >> 2;
    const int skc  = (tid & 3) ^ ((srow >> 1) & 3);
    const ushort* ga = xb + (size_t)(row0 + srow) * Dsz + skc * 8;
    const ushort* gb0 = Wt + (size_t)(col0 + srow) * Dsz + skc * 8;  // + z*Dsz*Dsz

    const int aoff = (quad ^ ((m16 >> 1) & 3)) * 8;

    // prologue: stage tile 0
    __builtin_amdgcn_global_load_lds((gptr_t)(ga),                    (lptr_t)(lsA[0] + tid * 8),        16, 0, 0);
    __builtin_amdgcn_global_load_lds((gptr_t)(ga + (size_t)64 * Dsz), (lptr_t)(lsA[0] + 2048 + tid * 8), 16, 0, 0);
#pragma unroll
    for (int z = 0; z < 3; z++) {
        const ushort* gb = gb0 + (size_t)z * Dsz * Dsz;
        __builtin_amdgcn_global_load_lds((gptr_t)(gb),                    (lptr_t)(lsB[0][z] + tid * 8),        16, 0, 0);
        __builtin_amdgcn_global_load_lds((gptr_t)(gb + (size_t)64 * Dsz), (lptr_t)(lsB[0][z] + 2048 + tid * 8), 16, 0, 0);
    }

    for (int k0 = 0; k0 < Dsz; k0 += 32) {
        const int cur = (k0 >> 5) & 1;
        __syncthreads();
        if (k0 + 32 < Dsz) {
            const int nxt = cur ^ 1;
            const int kn = k0 + 32;
            __builtin_amdgcn_global_load_lds((gptr_t)(ga + kn),                    (lptr_t)(lsA[nxt] + tid * 8),        16, 0, 0);
            __builtin_amdgcn_global_load_lds((gptr_t)(ga + kn + (size_t)64 * Dsz), (lptr_t)(lsA[nxt] + 2048 + tid * 8), 16, 0, 0);
#pragma unroll
            for (int z = 0; z < 3; z++) {
                const ushort* gb = gb0 + (size_t)z * Dsz * Dsz + kn;
                __builtin_amdgcn_global_load_lds((gptr_t)(gb),                    (lptr_t)(lsB[nxt][z] + tid * 8),        16, 0, 0);
                __builtin_amdgcn_global_load_lds((gptr_t)(gb + (size_t)64 * Dsz), (lptr_t)(lsB[nxt][z] + 2048 + tid * 8), 16, 0, 0);
            }
        }

        short8 af[4];
#pragma unroll
        for (int mi = 0; mi < 4; mi++)
            af[mi] = *(const short8*)&lsA[cur][(wr + mi * 16 + m16) * 32 + aoff];
#pragma unroll
        for (int z = 0; z < 3; z++) {
            short8 bfr[4];
#pragma unroll
            for (int ni = 0; ni < 4; ni++)
                bfr[ni] = *(const short8*)&lsB[cur][z][(wc + ni * 16 + m16) * 32 + aoff];
#pragma unroll
            for (int mi = 0; mi < 4; mi++)
#pragma unroll
                for (int ni = 0; ni < 4; ni++)
                    acc[z][mi][ni] = __builtin_amdgcn_mfma_f32_16x16x32_bf16(af[mi], bfr[ni], acc[z][mi][ni], 0, 0, 0);
        }
    }

    // epilogue. C/D: col = m16 (lane), row = quad*4 + reg.
    // z=0: Q row-major bf16, alpha=1/32 (score scale). z=1: K row-major bf16.
    // z=2: V transposed -> Vt[b][e][s] bf16 (replaces k_vt), ushort4 stores.
#pragma unroll
    for (int ni = 0; ni < 4; ni++) {
        const int gcol = col0 + wc + ni * 16 + m16;
        const float bqv = bq[gcol], bkv = bk[gcol], bvv = bv[gcol];
#pragma unroll
        for (int mi = 0; mi < 4; mi++) {
            const int grow0 = row0 + wr + mi * 16 + quad * 4;   // global row 0..8191
            ushort4 vpack;
#pragma unroll
            for (int j = 0; j < 4; j++) {
                QKV[(size_t)(grow0 + j) * Dsz + gcol] = f32_to_bf16((acc[0][mi][ni][j] + bqv) * 0.03125f);
                QKV[(size_t)(Bsz * Ssz) * Dsz + (size_t)(grow0 + j) * Dsz + gcol] = f32_to_bf16(acc[1][mi][ni][j] + bkv);
                const ushort vv = f32_to_bf16(acc[2][mi][ni][j] + bvv);
                if (j == 0) vpack.x = vv; else if (j == 1) vpack.y = vv;
                else if (j == 2) vpack.z = vv; else vpack.w = vv;
            }
            const int batch = grow0 >> 11;
            const int s0 = grow0 & (Ssz - 1);
            *(ushort4*)&Vt[(size_t)batch * Dsz * Ssz + (size_t)gcol * Ssz + s0] = vpack;
        }
    }
}

// ---------------------------------------------------------------------------
// Generic 128x128 GEMM (R7): C = A(MxK) * Bt(NxK)^T, bf16 in, fp32/bf16 out.
// ---------------------------------------------------------------------------
template <bool OUT_BF16>
__device__ __forceinline__ void gemm128(
    int bx, int by,
    const ushort* __restrict__ A, int lda,
    const ushort* __restrict__ Bt, int ldb,
    int K,
    void* __restrict__ Cout, int ldc,
    const float* __restrict__ bias, float alpha)
{
    __shared__ ushort lsA[2][128 * 32];
    __shared__ ushort lsB[2][128 * 32];

    const int tid  = threadIdx.x;
    const int row0 = by * 128;
    const int col0 = bx * 128;

    const int lane = tid & 63;
    const int wave = tid >> 6;
    const int wr   = (wave >> 1) * 64;
    const int wc   = (wave & 1) * 64;
    const int m16  = lane & 15;
    const int quad = lane >> 4;

    floatx4 acc[4][4];
#pragma unroll
    for (int i = 0; i < 4; i++)
#pragma unroll
        for (int j = 0; j < 4; j++) acc[i][j] = (floatx4){0.f, 0.f, 0.f, 0.f};

    const int srow = tid >> 2;
    const int skc  = (tid & 3) ^ ((srow >> 1) & 3);
    const ushort* ga = A  + (size_t)(row0 + srow) * lda + skc * 8;
    const ushort* gb = Bt + (size_t)(col0 + srow) * ldb + skc * 8;
    const int aoff = (quad ^ ((m16 >> 1) & 3)) * 8;

    __builtin_amdgcn_global_load_lds((gptr_t)(ga),                     (lptr_t)(lsA[0] + tid * 8),        16, 0, 0);
    __builtin_amdgcn_global_load_lds((gptr_t)(ga + (size_t)64 * lda), (lptr_t)(lsA[0] + 2048 + tid * 8), 16, 0, 0);
    __builtin_amdgcn_global_load_lds((gptr_t)(gb),                     (lptr_t)(lsB[0] + tid * 8),        16, 0, 0);
    __builtin_amdgcn_global_load_lds((gptr_t)(gb + (size_t)64 * ldb), (lptr_t)(lsB[0] + 2048 + tid * 8), 16, 0, 0);

    for (int k0 = 0; k0 < K; k0 += 32) {
        const int cur = (k0 >> 5) & 1;
        __syncthreads();
        if (k0 + 32 < K) {
            const int nxt = cur ^ 1;
            const int kn = k0 + 32;
            __builtin_amdgcn_global_load_lds((gptr_t)(ga + kn),                     (lptr_t)(lsA[nxt] + tid * 8),        16, 0, 0);
            __builtin_amdgcn_global_load_lds((gptr_t)(ga + kn + (size_t)64 * lda), (lptr_t)(lsA[nxt] + 2048 + tid * 8), 16, 0, 0);
            __builtin_amdgcn_global_load_lds((gptr_t)(gb + kn),                     (lptr_t)(lsB[nxt] + tid * 8),        16, 0, 0);
            __builtin_amdgcn_global_load_lds((gptr_t)(gb + kn + (size_t)64 * ldb), (lptr_t)(lsB[nxt] + 2048 + tid * 8), 16, 0, 0);
        }

        short8 af[4], bfr[4];
#pragma unroll
        for (int mi = 0; mi < 4; mi++)
            af[mi] = *(const short8*)&lsA[cur][(wr + mi * 16 + m16) * 32 + aoff];
#pragma unroll
        for (int ni = 0; ni < 4; ni++)
            bfr[ni] = *(const short8*)&lsB[cur][(wc + ni * 16 + m16) * 32 + aoff];
#pragma unroll
        for (int mi = 0; mi < 4; mi++)
#pragma unroll
            for (int ni = 0; ni < 4; ni++)
                acc[mi][ni] = __builtin_amdgcn_mfma_f32_16x16x32_bf16(af[mi], bfr[ni], acc[mi][ni], 0, 0, 0);
    }

#pragma unroll
    for (int ni = 0; ni < 4; ni++) {
        const int gcol = col0 + wc + ni * 16 + m16;
        const float bv = bias ? bias[gcol] : 0.0f;
#pragma unroll
        for (int mi = 0; mi < 4; mi++) {
            const int grow0 = row0 + wr + mi * 16 + quad * 4;
#pragma unroll
            for (int j = 0; j < 4; j++) {
                float v = (acc[mi][ni][j] + bv) * alpha;
                if (OUT_BF16)
                    ((ushort*)Cout)[(size_t)(grow0 + j) * ldc + gcol] = f32_to_bf16(v);
                else
                    ((float*)Cout)[(size_t)(grow0 + j) * ldc + gcol] = v;
            }
        }
    }
}

// ---------------------------------------------------------------------------
// prep: x fp32 -> bf16
__global__ __launch_bounds__(256) void k_cvt_x(const float* __restrict__ x, ushort* __restrict__ xb) {
    int i = (blockIdx.x * 256 + threadIdx.x) * 4;
    float4 v = *(const float4*)(x + i);
    ushort4 o;
    o.x = f32_to_bf16(v.x); o.y = f32_to_bf16(v.y);
    o.z = f32_to_bf16(v.z); o.w = f32_to_bf16(v.w);
    *(ushort4*)(xb + i) = o;
}

// prep: W [K][N] fp32 -> Wt [N][K] bf16, for each of Wq/Wk/Wv (z)
__global__ __launch_bounds__(256) void k_wt(const float* __restrict__ Wq, const float* __restrict__ Wk,
                                            const float* __restrict__ Wv, ushort* __restrict__ Wt) {
    __shared__ float tile[32][33];
    const int z = blockIdx.z;
    const float* W = (z == 0) ? Wq : ((z == 1) ? Wk : Wv);
    ushort* out = Wt + (size_t)z * Dsz * Dsz;
    const int kb = blockIdx.y * 32, nb = blockIdx.x * 32;
    const int tx = threadIdx.x, ty = threadIdx.y;   // 32x8
#pragma unroll
    for (int j = 0; j < 32; j += 8)
        tile[ty + j][tx] = W[(size_t)(kb + ty + j) * Dsz + nb + tx];
    __syncthreads();
#pragma unroll
    for (int j = 0; j < 32; j += 8)
        out[(size_t)(nb + ty + j) * Dsz + kb + tx] = f32_to_bf16(tile[tx][ty + j]);
}

// scores[b] = Q[b] @ K[b]^T. Grid (16,16,4), R7 XCD swizzle.
__global__ __launch_bounds__(256) void k_scores(const ushort* __restrict__ QKV, float* __restrict__ scores) {
    const int b = blockIdx.z;
    const int lin = blockIdx.y * 16 + blockIdx.x;
    const int c = lin & 7, m = lin >> 3;
    const int by = 2 * c + (m & 1);
    const int bx = m >> 1;
    const ushort* Q = QKV + (size_t)b * Ssz * Dsz;
    const ushort* Kb = QKV + (size_t)(Bsz + b) * Ssz * Dsz;
    gemm128<false>(bx, by, Q, Dsz, Kb, Dsz, Dsz, scores + (size_t)b * Ssz * Ssz, Ssz, nullptr, 1.0f);
}

// row softmax, fp32 row -> bf16 P written in place over the row's first half
__global__ __launch_bounds__(256) void k_softmax(float* __restrict__ scores) {
    const size_t row = blockIdx.x;
    float* rp = scores + row * Ssz;
    const int tid = threadIdx.x;
    float4 v0 = ((const float4*)rp)[tid];
    float4 v1 = ((const float4*)rp)[tid + 256];
    float m = fmaxf(fmaxf(fmaxf(v0.x, v0.y), fmaxf(v0.z, v0.w)),
                    fmaxf(fmaxf(v1.x, v1.y), fmaxf(v1.z, v1.w)));
#pragma unroll
    for (int o = 32; o > 0; o >>= 1) m = fmaxf(m, __shfl_down(m, o, 64));
    __shared__ float redm[4];
    if ((tid & 63) == 0) redm[tid >> 6] = m;
    __syncthreads();
    const float rm = fmaxf(fmaxf(redm[0], redm[1]), fmaxf(redm[2], redm[3]));
    v0.x = __expf(v0.x - rm); v0.y = __expf(v0.y - rm);
    v0.z = __expf(v0.z - rm); v0.w = __expf(v0.w - rm);
    v1.x = __expf(v1.x - rm); v1.y = __expf(v1.y - rm);
    v1.z = __expf(v1.z - rm); v1.w = __expf(v1.w - rm);
    float s = v0.x + v0.y + v0.z + v0.w + v1.x + v1.y + v1.z + v1.w;
#pragma unroll
    for (int o = 32; o > 0; o >>= 1) s += __shfl_down(s, o, 64);
    __shared__ float reds[4];
    if ((tid & 63) == 0) reds[tid >> 6] = s;
    __syncthreads();
    const float inv = 1.0f / (reds[0] + reds[1] + reds[2] + reds[3]);
    ushort4 o0, o1;
    o0.x = f32_to_bf16(v0.x * inv); o0.y = f32_to_bf16(v0.y * inv);
    o0.z = f32_to_bf16(v0.z * inv); o0.w = f32_to_bf16(v0.w * inv);
    o1.x = f32_to_bf16(v1.x * inv); o1.y = f32_to_bf16(v1.y * inv);
    o1.z = f32_to_bf16(v1.z * inv); o1.w = f32_to_bf16(v1.w * inv);
    ((ushort4*)rp)[tid] = o0;
    ((ushort4*)rp)[tid + 256] = o1;
}

// out[b] = P[b] @ V[b]. Grid (8,16,4), R7 XCD swizzle. Bt = Vt row-major [d][s].
__global__ __launch_bounds__(256) void k_pv(const float* __restrict__ scores, const ushort* __restrict__ Vt,
                                            float* __restrict__ out) {
    const int b = blockIdx.z;
    const int lin = blockIdx.y * 8 + blockIdx.x;
    const int c = lin & 7, m = lin >> 3;
    const int by = 2 * c + (m & 1);
    const int bx = m >> 1;
    const ushort* P = (const ushort*)(scores + (size_t)b * Ssz * Ssz);
    const ushort* Bt = Vt + (size_t)b * Dsz * Ssz;
    gemm128<false>(bx, by, P, 2 * Ssz, Bt, Ssz, Ssz, out + (size_t)b * Ssz * Dsz, Dsz, nullptr, 1.0f);
}

// ---------------------------------------------------------------------------
extern "C" void kernel_launch(void* const* d_in, const int* in_sizes, int n_in,
                              void* d_out, int out_size, void* d_ws, size_t ws_size,
                              hipStream_t stream) {
    const float* x  = (const float*)d_in[0];
    const float* Wq = (const float*)d_in[1];
    const float* bq = (const float*)d_in[2];
    const float* Wk = (const float*)d_in[3];
    const float* bk = (const float*)d_in[4];
    const float* Wv = (const float*)d_in[5];
    const float* bv = (const float*)d_in[6];
    float* out = (float*)d_out;

    // workspace layout (bytes)
    char* ws = (char*)d_ws;
    ushort* xb     = (ushort*)(ws);                                   // 16,777,216
    ushort* Wt     = (ushort*)(ws + 16777216);                        //  6,291,456
    ushort* QKV    = (ushort*)(ws + 23068672);                        // 50,331,648 (V region unused)
    ushort* Vt     = (ushort*)(ws + 73400320);                        // 16,777,216
    float*  scores = (float*) (ws + 90177536);                        // 67,108,864 -> 157,286,400 total

    k_cvt_x<<<dim3(Bsz * Ssz * Dsz / (256 * 4)), dim3(256), 0, stream>>>(x, xb);
    k_wt<<<dim3(32, 32, 3), dim3(32, 8), 0, stream>>>(Wq, Wk, Wv, Wt);
    k_qkv<<<dim3(Dsz / 128, Bsz * Ssz / 128), dim3(256), 0, stream>>>(xb, Wt, bq, bk, bv, QKV, Vt);
    k_scores<<<dim3(Ssz / 128, Ssz / 128, Bsz), dim3(256), 0, stream>>>(QKV, scores);
    k_softmax<<<dim3(Bsz * Ssz), dim3(256), 0, stream>>>(scores);
    k_pv<<<dim3(Dsz / 128, Ssz / 128, Bsz), dim3(256), 0, stream>>>(scores, Vt, out);
}